// Round 13
// baseline (752.265 us; speedup 1.0000x reference)
//
#include <hip/hip_runtime.h>
#include <hip/hip_bf16.h>
#include <math.h>
#include <float.h>

typedef __hip_bfloat16 bf16;
using bf16x8 = __attribute__((ext_vector_type(8))) __bf16;
using f32x4  = __attribute__((ext_vector_type(4))) float;

constexpr int BATCH = 4;
constexpr int SEQ   = 2048;
constexpr int SEQ1  = 2049;
constexpr int DIN   = 768;
constexpr int DIMC  = 512;
constexpr int DEPTH = 2;
constexpr int NHEAD = 8;
constexpr int DHEAD = 64;
constexpr int ROWS  = BATCH * SEQ1;   // 8196
constexpr int VKP   = 2112;           // padded key stride for VT (33 tiles * 64)
constexpr float ATT_SCALE = 0.125f;
constexpr float NEGBIG = -1e30f;

__device__ __forceinline__ bf16x8 ld_frag(const bf16* p) { return *(const bf16x8*)p; }

// async global->LDS, 16B per lane; dest = wave-uniform base + lane*16
__device__ __forceinline__ void g2lds16(const bf16* g, bf16* l) {
    __builtin_amdgcn_global_load_lds(
        (const __attribute__((address_space(1))) void*)g,
        (__attribute__((address_space(3))) void*)l, 16, 0, 0);
}

// ---------------- cast fp32 -> bf16 (x stem input) ----------------
__global__ __launch_bounds__(256) void cast_kernel(const float* __restrict__ src,
                                                   bf16* __restrict__ dst, int n4) {
    int i = blockIdx.x * 256 + threadIdx.x;
    if (i < n4) {
        float4 v = ((const float4*)src)[i];
        dst[i * 4 + 0] = __float2bfloat16(v.x);
        dst[i * 4 + 1] = __float2bfloat16(v.y);
        dst[i * 4 + 2] = __float2bfloat16(v.z);
        dst[i * 4 + 3] = __float2bfloat16(v.w);
    }
}

// ---------------- weight transpose + cast: src[R][C] fp32 -> dst[C][R] bf16, z batches ----------------
__global__ __launch_bounds__(256) void wt_transpose_kernel(
    const float* __restrict__ src, bf16* __restrict__ dst,
    int R, int C, long zstride) {
    __shared__ bf16 tile[32][33];
    int z = blockIdx.z;
    const float* s = src + (size_t)z * zstride;
    bf16* d = dst + (size_t)z * zstride;
    int tx = threadIdx.x, ty = threadIdx.y;
    int c0 = blockIdx.x * 32, r0 = blockIdx.y * 32;
    int c = c0 + tx;
#pragma unroll
    for (int rr = ty; rr < 32; rr += 8) {
        int r = r0 + rr;
        tile[rr][tx] = (r < R && c < C) ? __float2bfloat16(s[(size_t)r * C + c])
                                        : __float2bfloat16(0.f);
    }
    __syncthreads();
    int rc = r0 + tx;
#pragma unroll
    for (int cc = ty; cc < 32; cc += 8) {
        int oc = c0 + cc;
        if (rc < R && oc < C) d[(size_t)oc * R + rc] = tile[tx][cc];
    }
}

// ---------------- merged 512x512 weight transposes: z in [0,6) = (which, layer) ----------------
__global__ __launch_bounds__(256) void wt3_transpose_kernel(
    const float* __restrict__ w0, const float* __restrict__ w1, const float* __restrict__ w2,
    bf16* __restrict__ dst) {
    __shared__ bf16 tile[32][33];
    int z = blockIdx.z;
    const float* srcs[3] = {w0, w1, w2};
    const float* s = srcs[z >> 1] + (size_t)(z & 1) * DIMC * DIMC;
    bf16* d = dst + (size_t)z * DIMC * DIMC;
    int tx = threadIdx.x, ty = threadIdx.y;
    int c0 = blockIdx.x * 32, r0 = blockIdx.y * 32;
    int c = c0 + tx;
#pragma unroll
    for (int rr = ty; rr < 32; rr += 8)
        tile[rr][tx] = __float2bfloat16(s[(size_t)(r0 + rr) * DIMC + c]);
    __syncthreads();
    int rc = r0 + tx;
#pragma unroll
    for (int cc = ty; cc < 32; cc += 8)
        d[(size_t)(c0 + cc) * DIMC + rc] = tile[tx][cc];
}

// ---------------- V transpose: QKV V-part [SEQ1][64] per (b,h) -> VT[b*8+h][64][VKP] ----------------
__global__ __launch_bounds__(256) void vt_transpose_kernel(
    const bf16* __restrict__ QKV, bf16* __restrict__ VT) {
    __shared__ bf16 tile[32][33];
    int z = blockIdx.z;                       // b*8+h
    int bb = z >> 3, hh = z & 7;
    const bf16* s = QKV + (size_t)bb * SEQ1 * 1536 + 1024 + hh * 64;
    bf16* d = VT + (size_t)z * 64 * VKP;
    int tx = threadIdx.x, ty = threadIdx.y;
    int c0 = blockIdx.x * 32, r0 = blockIdx.y * 32;   // c: dim, r: key
    int c = c0 + tx;
#pragma unroll
    for (int rr = ty; rr < 32; rr += 8) {
        int r = r0 + rr;
        tile[rr][tx] = (r < SEQ1) ? s[(size_t)r * 1536 + c] : __float2bfloat16(0.f);
    }
    __syncthreads();
    int rc = r0 + tx;
#pragma unroll
    for (int cc = ty; cc < 32; cc += 8) {
        int oc = c0 + cc;
        if (rc < VKP) d[(size_t)oc * VKP + rc] = tile[tx][cc];
    }
}

// ---------------- cls fill (fp32) ----------------
__global__ void cls_fill_kernel(const float* __restrict__ cls, float* __restrict__ X) {
    int b = blockIdx.x;
    for (int d = threadIdx.x; d < DIMC; d += blockDim.x)
        X[(size_t)b * SEQ1 * DIMC + d] = cls[d];
}

// ---------------- MFMA GEMM: C[M,N] = A[M,K](bf16) @ Bt[N,K]^T, BM x 128 tile ----------------
template<int BM, bool GELU_, bool RESID, bool REMAP, bool OBF>
__global__ __launch_bounds__(256) void gemm_bt(
    const bf16* __restrict__ A, const bf16* __restrict__ Bt,
    const float* __restrict__ bias, const float* __restrict__ resid,
    float* __restrict__ Cf, bf16* __restrict__ Ch, int M, int N, int K) {
    constexpr int MI = BM / 32;               // m-tiles per wave
    __shared__ __align__(16) bf16 As[BM * 32];
    __shared__ __align__(16) bf16 Bs[4096];
    int tid = threadIdx.x;
    int ln = tid & 63, wv = tid >> 6;
    int wr = wv >> 1, wc = wv & 1;
    int l15 = ln & 15, l4 = ln >> 4;
    int m0 = blockIdx.y * BM, n0 = blockIdx.x * 128;

    f32x4 acc[MI][4];
#pragma unroll
    for (int i = 0; i < MI; ++i)
#pragma unroll
        for (int j = 0; j < 4; ++j) acc[i][j] = {0.f, 0.f, 0.f, 0.f};

    int aslot[MI], bslot[4];
#pragma unroll
    for (int i = 0; i < MI; ++i) {
        int m = wr * (BM / 2) + i * 16 + l15;
        aslot[i] = m * 4 + (l4 ^ ((m >> 1) & 3));
    }
#pragma unroll
    for (int j = 0; j < 4; ++j) {
        int n = wc * 64 + j * 16 + l15;
        bslot[j] = n * 4 + (l4 ^ ((n >> 1) & 3));
    }

    for (int k0 = 0; k0 < K; k0 += 32) {
#pragma unroll
        for (int r = 0; r < BM / 64; ++r) {
            int s = r * 256 + tid;
            int m = s >> 2, c = s & 3;
            int kb = c ^ ((m >> 1) & 3);
            int gm = m0 + m; if (gm > M - 1) gm = M - 1;   // clamp; results discarded at store
            g2lds16(A + (size_t)gm * K + k0 + kb * 8, &As[s * 8]);
        }
#pragma unroll
        for (int r = 0; r < 2; ++r) {
            int s = r * 256 + tid;
            int n = s >> 2, c = s & 3;
            int kb = c ^ ((n >> 1) & 3);
            g2lds16(Bt + (size_t)(n0 + n) * K + k0 + kb * 8, &Bs[s * 8]);
        }
        __syncthreads();
        bf16x8 af[MI], bfr[4];
#pragma unroll
        for (int i = 0; i < MI; ++i) af[i] = ld_frag(&As[aslot[i] * 8]);
#pragma unroll
        for (int j = 0; j < 4; ++j) bfr[j] = ld_frag(&Bs[bslot[j] * 8]);
#pragma unroll
        for (int i = 0; i < MI; ++i)
#pragma unroll
            for (int j = 0; j < 4; ++j)
                acc[i][j] = __builtin_amdgcn_mfma_f32_16x16x32_bf16(af[i], bfr[j], acc[i][j], 0, 0, 0);
        __syncthreads();
    }

#pragma unroll
    for (int i = 0; i < MI; ++i) {
#pragma unroll
        for (int j = 0; j < 4; ++j) {
            int gn = n0 + wc * 64 + j * 16 + l15;
            float bb = bias ? bias[gn] : 0.f;
#pragma unroll
            for (int r = 0; r < 4; ++r) {
                int gm = m0 + wr * (BM / 2) + i * 16 + l4 * 4 + r;
                if (gm >= M) continue;
                float v = acc[i][j][r] + bb;
                if (GELU_) v = 0.5f * v * (1.f + erff(v * 0.70710678118654752f));
                size_t orow = gm;
                if (REMAP) { int b_ = gm >> 11; orow = (size_t)b_ * SEQ1 + (gm & 2047) + 1; }
                size_t oi = orow * (size_t)N + gn;
                if (RESID) v += resid[oi];
                if (OBF) Ch[oi] = __float2bfloat16(v); else Cf[oi] = v;
            }
        }
    }
}

// ---------------- LayerNorm: one wave per row, no LDS, no barriers ----------------
__global__ __launch_bounds__(256) void ln_kernel(const float* __restrict__ Xin, bf16* __restrict__ Xout,
                          const float* __restrict__ g, const float* __restrict__ bb) {
    int wv = threadIdx.x >> 6, ln = threadIdx.x & 63;
    int row = blockIdx.x * 4 + wv;
    if (row >= ROWS) return;
    const float* xr = Xin + (size_t)row * DIMC + ln * 8;
    float4 a = *(const float4*)xr;
    float4 c = *(const float4*)(xr + 4);
    float s = a.x + a.y + a.z + a.w + c.x + c.y + c.z + c.w;
#pragma unroll
    for (int off = 1; off < 64; off <<= 1) s += __shfl_xor(s, off, 64);
    float mean = s * (1.f / 512.f);
    float d[8] = {a.x - mean, a.y - mean, a.z - mean, a.w - mean,
                  c.x - mean, c.y - mean, c.z - mean, c.w - mean};
    float var = 0.f;
#pragma unroll
    for (int e = 0; e < 8; ++e) var += d[e] * d[e];
#pragma unroll
    for (int off = 1; off < 64; off <<= 1) var += __shfl_xor(var, off, 64);
    float rinv = rsqrtf(var * (1.f / 512.f) + 1e-5f);
    const float* gp = g + ln * 8;
    const float* bp = bb + ln * 8;
    float4 g0 = *(const float4*)gp, g1 = *(const float4*)(gp + 4);
    float4 b0 = *(const float4*)bp, b1 = *(const float4*)(bp + 4);
    float gg[8] = {g0.x, g0.y, g0.z, g0.w, g1.x, g1.y, g1.z, g1.w};
    float bbv[8] = {b0.x, b0.y, b0.z, b0.w, b1.x, b1.y, b1.z, b1.w};
    union { unsigned short u[8]; uint4 v; } ou;
#pragma unroll
    for (int e = 0; e < 8; ++e)
        ou.u[e] = __builtin_bit_cast(unsigned short, __float2bfloat16(d[e] * rinv * gg[e] + bbv[e]));
    *(uint4*)(Xout + (size_t)row * DIMC + ln * 8) = ou.v;
}

// ---------------- MFMA flash attention v6: 3D grid (R11 mapping) + hoisted offsets + no clamp ----------------
__global__ __launch_bounds__(256, 5) void attn_kernel(
    const bf16* __restrict__ QKV, const bf16* __restrict__ VT,
    const int* __restrict__ lens, bf16* __restrict__ O) {
    __shared__ __align__(16) bf16 Ks[2][4096];
    __shared__ __align__(16) bf16 Vs[2][4096];   // V^T tile: [dim][key]
    int tid = threadIdx.x, ln = tid & 63, wv = tid >> 6;
    int l15 = ln & 15, l4 = ln >> 4;
    int q0 = blockIdx.x * 64, h = blockIdx.y, b = blockIdx.z;
    int len1 = lens[b] + 1;
    const bf16* qkv_b = QKV + (size_t)b * SEQ1 * 1536;
    const bf16* vt_b  = VT + (size_t)(b * 8 + h) * 64 * VKP;

    uint4 z4 = make_uint4(0u, 0u, 0u, 0u);
    uint4 q0v = z4, q1v = z4;
    int qrow = q0 + wv * 16 + l15;
    if (qrow < SEQ1) {
        const bf16* qp = qkv_b + (size_t)qrow * 1536 + h * 64 + l4 * 8;
        q0v = *(const uint4*)qp;
        q1v = *(const uint4*)(qp + 32);
    }
    bf16x8 bq0 = __builtin_bit_cast(bf16x8, q0v);
    bf16x8 bq1 = __builtin_bit_cast(bf16x8, q1v);
    bool qpad = (qrow >= len1);

    float mrun = NEGBIG, lrun = 0.f;
    f32x4 oaccT[4];
#pragma unroll
    for (int t = 0; t < 4; ++t) oaccT[t] = {0.f, 0.f, 0.f, 0.f};

    // --- hoisted LDS element offsets (loop-invariant) ---
    int koff[2][2][2];   // [pb][s][half]
#pragma unroll
    for (int pb = 0; pb < 2; ++pb)
#pragma unroll
        for (int s = 0; s < 2; ++s) {
            int R = pb * 32 + s * 16 + l15;
            koff[pb][s][0] = (R * 8 + (l4 ^ (R & 7))) * 8;
            koff[pb][s][1] = (R * 8 + ((l4 + 4) ^ (R & 7))) * 8;
        }
    int voff[2][4];      // [pb][t]
#pragma unroll
    for (int pb = 0; pb < 2; ++pb)
#pragma unroll
        for (int t = 0; t < 4; ++t) {
            int VR = t * 16 + l15;
            voff[pb][t] = (VR * 8 + ((pb * 4 + l4) ^ (VR & 7))) * 8;
        }

    uint4 kr[2], vr[2];
    int srow[2], kslot[2], vslot[2];
    const bf16* kg[2];
    const bf16* vg[2];
#pragma unroll
    for (int rr = 0; rr < 2; ++rr) {
        int idx = rr * 256 + tid;
        int row = idx >> 3, seg = idx & 7;
        srow[rr] = row;
        int pb = row >> 5, w = row & 31;
        int krow = pb * 32 + ((w >> 2) & 1) * 16 + (w >> 3) * 4 + (w & 3);  // permuted K row
        kslot[rr] = (krow * 8 + (seg ^ (krow & 7))) * 8;
        vslot[rr] = (row * 8 + (seg ^ (row & 7))) * 8;
        kg[rr] = qkv_b + (size_t)row * 1536 + 512 + h * 64 + seg * 8;
        vg[rr] = vt_b + (size_t)row * VKP + seg * 8;
    }

    // prologue: tile 0 (rows 0..63 always < SEQ1)
#pragma unroll
    for (int rr = 0; rr < 2; ++rr) {
        kr[rr] = *(const uint4*)kg[rr];
        vr[rr] = *(const uint4*)vg[rr];
        kg[rr] += 64 * 1536; vg[rr] += 64;
    }
#pragma unroll
    for (int rr = 0; rr < 2; ++rr) {
        *(uint4*)&Ks[0][kslot[rr]] = kr[rr];
        *(uint4*)&Vs[0][vslot[rr]] = vr[rr];
    }
    __syncthreads();

    for (int kt = 0; kt < 33; ++kt) {
        int k0 = kt * 64;
        int buf = kt & 1;
        const bf16* ksb = &Ks[buf][0];
        const bf16* vsb = &Vs[buf][0];
        if (kt < 32) {
            int kn = k0 + 64;
#pragma unroll
            for (int rr = 0; rr < 2; ++rr) {
                kr[rr] = (kn + srow[rr] < SEQ1) ? *(const uint4*)kg[rr] : z4;
                vr[rr] = *(const uint4*)vg[rr];
                kg[rr] += 64 * 1536; vg[rr] += 64;
            }
        }

        // S^T = K Q^T
        f32x4 sacc[2][2];
#pragma unroll
        for (int pb = 0; pb < 2; ++pb)
#pragma unroll
            for (int s = 0; s < 2; ++s) {
                f32x4 a = {0.f, 0.f, 0.f, 0.f};
                bf16x8 kf0 = ld_frag(ksb + koff[pb][s][0]);
                bf16x8 kf1 = ld_frag(ksb + koff[pb][s][1]);
                a = __builtin_amdgcn_mfma_f32_16x16x32_bf16(kf0, bq0, a, 0, 0, 0);
                a = __builtin_amdgcn_mfma_f32_16x16x32_bf16(kf1, bq1, a, 0, 0, 0);
                sacc[pb][s] = a;
            }

        // online softmax (in-place in sacc); no clamp: __expf(-1e30)=0
        bool needmask = (k0 + 64 > len1) || (kt == 32);
        float mx = NEGBIG;
#pragma unroll
        for (int pb = 0; pb < 2; ++pb)
#pragma unroll
            for (int s = 0; s < 2; ++s)
#pragma unroll
                for (int r = 0; r < 4; ++r) {
                    float v = sacc[pb][s][r] * ATT_SCALE;
                    if (needmask) {
                        int j = k0 + pb * 32 + l4 * 8 + s * 4 + r;
                        if (j >= SEQ1 || (qpad && j >= len1)) v = NEGBIG;
                    }
                    sacc[pb][s][r] = v;
                    mx = fmaxf(mx, v);
                }
        mx = fmaxf(mx, __shfl_xor(mx, 16, 64));
        mx = fmaxf(mx, __shfl_xor(mx, 32, 64));
        float mnew = fmaxf(mrun, mx);
        float alpha = __expf(mrun - mnew);
        float rs = 0.f;
        unsigned short pk[2][8];
#pragma unroll
        for (int pb = 0; pb < 2; ++pb)
#pragma unroll
            for (int s = 0; s < 2; ++s)
#pragma unroll
                for (int r = 0; r < 4; ++r) {
                    float p = __expf(sacc[pb][s][r] - mnew);
                    rs += p;
                    pk[pb][s * 4 + r] = __builtin_bit_cast(unsigned short, __float2bfloat16(p));
                }
        rs += __shfl_xor(rs, 16, 64);
        rs += __shfl_xor(rs, 32, 64);
        lrun = lrun * alpha + rs;
        mrun = mnew;
#pragma unroll
        for (int t = 0; t < 4; ++t) {
            oaccT[t][0] *= alpha; oaccT[t][1] *= alpha;
            oaccT[t][2] *= alpha; oaccT[t][3] *= alpha;
        }

        // O^T += V^T P^T
#pragma unroll
        for (int pb = 0; pb < 2; ++pb) {
            union { unsigned short u[8]; bf16x8 v; } pu;
#pragma unroll
            for (int e = 0; e < 8; ++e) pu.u[e] = pk[pb][e];
            bf16x8 pf = pu.v;
#pragma unroll
            for (int t = 0; t < 4; ++t) {
                bf16x8 vf = ld_frag(vsb + voff[pb][t]);
                oaccT[t] = __builtin_amdgcn_mfma_f32_16x16x32_bf16(vf, pf, oaccT[t], 0, 0, 0);
            }
        }

        if (kt < 32) {
            bf16* kob = &Ks[buf ^ 1][0];
            bf16* vob = &Vs[buf ^ 1][0];
#pragma unroll
            for (int rr = 0; rr < 2; ++rr) {
                *(uint4*)&kob[kslot[rr]] = kr[rr];
                *(uint4*)&vob[vslot[rr]] = vr[rr];
            }
        }
        __syncthreads();
    }

    if (qrow < SEQ1) {
        float rl = (lrun > 0.f) ? 1.f / lrun : 0.f;
        bf16* orow = O + ((size_t)b * SEQ1 + qrow) * DIMC + h * 64;
#pragma unroll
        for (int t = 0; t < 4; ++t) {
            union { unsigned short u[4]; uint2 v; } ou;
#pragma unroll
            for (int r = 0; r < 4; ++r)
                ou.u[r] = __builtin_bit_cast(unsigned short, __float2bfloat16(oaccT[t][r] * rl));
            *(uint2*)&orow[t * 16 + l4 * 4] = ou.v;
        }
    }
}

// ---------------- fused final LN + head (cls row only), fp32 ----------------
__global__ __launch_bounds__(256) void head_kernel(const float* __restrict__ X,
                            const float* __restrict__ g, const float* __restrict__ bb,
                            const float* __restrict__ hw, const float* __restrict__ hb,
                            float* __restrict__ out) {
    int b = blockIdx.x, t = threadIdx.x;
    const float* xr = X + (size_t)b * SEQ1 * DIMC;
    float v0 = xr[t], v1 = xr[t + 256];
    __shared__ float red[256];
    red[t] = v0 + v1;
    __syncthreads();
    for (int w = 128; w > 0; w >>= 1) { if (t < w) red[t] += red[t + w]; __syncthreads(); }
    float mean = red[0] * (1.f / 512.f);
    __syncthreads();
    float d0 = v0 - mean, d1 = v1 - mean;
    red[t] = d0 * d0 + d1 * d1;
    __syncthreads();
    for (int w = 128; w > 0; w >>= 1) { if (t < w) red[t] += red[t + w]; __syncthreads(); }
    float rinv = rsqrtf(red[0] * (1.f / 512.f) + 1e-5f);
    __syncthreads();
    float xn0 = d0 * rinv * g[t] + bb[t];
    float xn1 = d1 * rinv * g[t + 256] + bb[t + 256];
    float p0 = xn0 * hw[t * 2]     + xn1 * hw[(t + 256) * 2];
    float p1 = xn0 * hw[t * 2 + 1] + xn1 * hw[(t + 256) * 2 + 1];
    __shared__ float r0[256], r1[256];
    r0[t] = p0; r1[t] = p1;
    __syncthreads();
    for (int w = 128; w > 0; w >>= 1) { if (t < w) { r0[t] += r0[t + w]; r1[t] += r1[t + w]; } __syncthreads(); }
    if (t == 0) {
        out[b * 2 + 0] = r0[0] + hb[0];
        out[b * 2 + 1] = r1[0] + hb[1];
    }
}

extern "C" void kernel_launch(void* const* d_in, const int* in_sizes, int n_in,
                              void* d_out, int out_size, void* d_ws, size_t ws_size,
                              hipStream_t stream) {
    const float* x      = (const float*)d_in[0];
    const int*   lens   = (const int*)d_in[1];
    const float* cls    = (const float*)d_in[2];
    const float* fc_w   = (const float*)d_in[3];
    const float* fc_b   = (const float*)d_in[4];
    const float* ln1_g  = (const float*)d_in[5];
    const float* ln1_b  = (const float*)d_in[6];
    const float* qkv_w  = (const float*)d_in[7];
    const float* out_w  = (const float*)d_in[8];
    const float* out_b  = (const float*)d_in[9];
    const float* ln2_g  = (const float*)d_in[10];
    const float* ln2_b  = (const float*)d_in[11];
    const float* ff1_w  = (const float*)d_in[12];
    const float* ff1_b  = (const float*)d_in[13];
    const float* ff2_w  = (const float*)d_in[14];
    const float* ff2_b  = (const float*)d_in[15];
    const float* lnf_g  = (const float*)d_in[16];
    const float* lnf_b  = (const float*)d_in[17];
    const float* head_w = (const float*)d_in[18];
    const float* head_b = (const float*)d_in[19];
    float* out = (float*)d_out;

    char* w = (char*)d_ws;
    float* X    = (float*)w;  w += (size_t)ROWS * DIMC * 4;
    bf16*  XNh  = (bf16*)w;   w += (size_t)ROWS * DIMC * 2;
    bf16*  QKVh = (bf16*)w;   w += (size_t)ROWS * 1536 * 2;
    bf16*  Obh  = (bf16*)w;   w += (size_t)ROWS * DIMC * 2;
    bf16*  xbf  = (bf16*)w;   w += (size_t)BATCH * SEQ * DIN * 2;
    bf16*  VT   = xbf;        // alias: xbf dead after stem gemm
    bf16*  fc_wt  = (bf16*)w;
    bf16*  qkv_wt = fc_wt  + (size_t)DIN * DIMC;
    bf16*  out_wt = qkv_wt + (size_t)2 * DIMC * 1536;
    bf16*  ff1_wt = out_wt + (size_t)2 * DIMC * DIMC;
    bf16*  ff2_wt = ff1_wt + (size_t)2 * DIMC * DIMC;
    bf16*  Hbh  = Obh;

    dim3 blk(256);
    dim3 tb(32, 8);

    cast_kernel<<<dim3((BATCH * SEQ * DIN / 4 + 255) / 256), blk, 0, stream>>>(
        x, xbf, BATCH * SEQ * DIN / 4);

    wt_transpose_kernel<<<dim3(16, 24, 1), tb, 0, stream>>>(fc_w,  fc_wt,  DIN,  DIMC, (long)DIN * DIMC);
    wt_transpose_kernel<<<dim3(48, 16, 2), tb, 0, stream>>>(qkv_w, qkv_wt, DIMC, 1536, (long)DIMC * 1536);
    wt3_transpose_kernel<<<dim3(16, 16, 6), tb, 0, stream>>>(out_w, ff1_w, ff2_w, out_wt);

    // stem: fc + gelu -> X fp32 (remapped rows), BM=64 -> 512 blocks
    gemm_bt<64, true, false, true, false><<<dim3(4, 128), blk, 0, stream>>>(
        xbf, fc_wt, fc_b, nullptr, X, nullptr, BATCH * SEQ, DIMC, DIN);
    cls_fill_kernel<<<dim3(BATCH), blk, 0, stream>>>(cls, X);

    for (int l = 0; l < DEPTH; ++l) {
        ln_kernel<<<dim3((ROWS + 3) / 4), blk, 0, stream>>>(X, XNh, ln1_g + l * DIMC, ln1_b + l * DIMC);
        // qkv: N=1536, BM=64 -> 1548 blocks (occupancy; R10 evidence on this M)
        gemm_bt<64, false, false, false, true><<<dim3(12, 129), blk, 0, stream>>>(
            XNh, qkv_wt + (size_t)l * DIMC * 1536, nullptr, nullptr, nullptr, QKVh, ROWS, 1536, DIMC);
        vt_transpose_kernel<<<dim3(2, 66, 32), tb, 0, stream>>>(QKVh, VT);
        attn_kernel<<<dim3(33, NHEAD, BATCH), blk, 0, stream>>>(QKVh, VT, lens, Obh);
        gemm_bt<64, false, true, false, false><<<dim3(4, 129), blk, 0, stream>>>(
            Obh, out_wt + (size_t)l * DIMC * DIMC, out_b + l * DIMC, X, X, nullptr, ROWS, DIMC, DIMC);
        ln_kernel<<<dim3((ROWS + 3) / 4), blk, 0, stream>>>(X, XNh, ln2_g + l * DIMC, ln2_b + l * DIMC);
        gemm_bt<64, true, false, false, true><<<dim3(4, 129), blk, 0, stream>>>(
            XNh, ff1_wt + (size_t)l * DIMC * DIMC, ff1_b + l * DIMC, nullptr, nullptr, Hbh, ROWS, DIMC, DIMC);
        gemm_bt<64, false, true, false, false><<<dim3(4, 129), blk, 0, stream>>>(
            Hbh, ff2_wt + (size_t)l * DIMC * DIMC, ff2_b + l * DIMC, X, X, nullptr, ROWS, DIMC, DIMC);
    }
    head_kernel<<<dim3(BATCH), blk, 0, stream>>>(X, lnf_g, lnf_b, head_w, head_b, out);
}

// Round 14
// 553.789 us; speedup vs baseline: 1.3584x; 1.3584x over previous
//
#include <hip/hip_runtime.h>
#include <hip/hip_bf16.h>
#include <math.h>
#include <float.h>

typedef __hip_bfloat16 bf16;
using bf16x8 = __attribute__((ext_vector_type(8))) __bf16;
using f32x4  = __attribute__((ext_vector_type(4))) float;

constexpr int BATCH = 4;
constexpr int SEQ   = 2048;
constexpr int SEQ1  = 2049;
constexpr int DIN   = 768;
constexpr int DIMC  = 512;
constexpr int DEPTH = 2;
constexpr int NHEAD = 8;
constexpr int DHEAD = 64;
constexpr int ROWS  = BATCH * SEQ1;   // 8196
constexpr int VKP   = 2112;           // padded key stride for VT (33 tiles * 64)
constexpr float ATT_SCALE = 0.125f;
constexpr float NEGBIG = -1e30f;

__device__ __forceinline__ bf16x8 ld_frag(const bf16* p) { return *(const bf16x8*)p; }

// async global->LDS, 16B per lane; dest = wave-uniform base + lane*16
__device__ __forceinline__ void g2lds16(const bf16* g, bf16* l) {
    __builtin_amdgcn_global_load_lds(
        (const __attribute__((address_space(1))) void*)g,
        (__attribute__((address_space(3))) void*)l, 16, 0, 0);
}

// ---------------- cast fp32 -> bf16 (x stem input) ----------------
__global__ __launch_bounds__(256) void cast_kernel(const float* __restrict__ src,
                                                   bf16* __restrict__ dst, int n4) {
    int i = blockIdx.x * 256 + threadIdx.x;
    if (i < n4) {
        float4 v = ((const float4*)src)[i];
        dst[i * 4 + 0] = __float2bfloat16(v.x);
        dst[i * 4 + 1] = __float2bfloat16(v.y);
        dst[i * 4 + 2] = __float2bfloat16(v.z);
        dst[i * 4 + 3] = __float2bfloat16(v.w);
    }
}

// ---------------- weight transpose + cast: src[R][C] fp32 -> dst[C][R] bf16, z batches ----------------
__global__ __launch_bounds__(256) void wt_transpose_kernel(
    const float* __restrict__ src, bf16* __restrict__ dst,
    int R, int C, long zstride) {
    __shared__ bf16 tile[32][33];
    int z = blockIdx.z;
    const float* s = src + (size_t)z * zstride;
    bf16* d = dst + (size_t)z * zstride;
    int tx = threadIdx.x, ty = threadIdx.y;
    int c0 = blockIdx.x * 32, r0 = blockIdx.y * 32;
    int c = c0 + tx;
#pragma unroll
    for (int rr = ty; rr < 32; rr += 8) {
        int r = r0 + rr;
        tile[rr][tx] = (r < R && c < C) ? __float2bfloat16(s[(size_t)r * C + c])
                                        : __float2bfloat16(0.f);
    }
    __syncthreads();
    int rc = r0 + tx;
#pragma unroll
    for (int cc = ty; cc < 32; cc += 8) {
        int oc = c0 + cc;
        if (rc < R && oc < C) d[(size_t)oc * R + rc] = tile[tx][cc];
    }
}

// ---------------- merged 512x512 weight transposes: z in [0,6) = (which, layer) ----------------
__global__ __launch_bounds__(256) void wt3_transpose_kernel(
    const float* __restrict__ w0, const float* __restrict__ w1, const float* __restrict__ w2,
    bf16* __restrict__ dst) {
    __shared__ bf16 tile[32][33];
    int z = blockIdx.z;
    const float* srcs[3] = {w0, w1, w2};
    const float* s = srcs[z >> 1] + (size_t)(z & 1) * DIMC * DIMC;
    bf16* d = dst + (size_t)z * DIMC * DIMC;
    int tx = threadIdx.x, ty = threadIdx.y;
    int c0 = blockIdx.x * 32, r0 = blockIdx.y * 32;
    int c = c0 + tx;
#pragma unroll
    for (int rr = ty; rr < 32; rr += 8)
        tile[rr][tx] = __float2bfloat16(s[(size_t)(r0 + rr) * DIMC + c]);
    __syncthreads();
    int rc = r0 + tx;
#pragma unroll
    for (int cc = ty; cc < 32; cc += 8)
        d[(size_t)(c0 + cc) * DIMC + rc] = tile[tx][cc];
}

// ---------------- cls fill (fp32) ----------------
__global__ void cls_fill_kernel(const float* __restrict__ cls, float* __restrict__ X) {
    int b = blockIdx.x;
    for (int d = threadIdx.x; d < DIMC; d += blockDim.x)
        X[(size_t)b * SEQ1 * DIMC + d] = cls[d];
}

// ---------------- MFMA GEMM: C[M,N] = A[M,K](bf16) @ Bt[N,K]^T, BM x 128 tile ----------------
template<int BM, bool GELU_, bool RESID, bool REMAP, bool OBF>
__global__ __launch_bounds__(256) void gemm_bt(
    const bf16* __restrict__ A, const bf16* __restrict__ Bt,
    const float* __restrict__ bias, const float* __restrict__ resid,
    float* __restrict__ Cf, bf16* __restrict__ Ch, int M, int N, int K) {
    constexpr int MI = BM / 32;               // m-tiles per wave
    __shared__ __align__(16) bf16 As[BM * 32];
    __shared__ __align__(16) bf16 Bs[4096];
    int tid = threadIdx.x;
    int ln = tid & 63, wv = tid >> 6;
    int wr = wv >> 1, wc = wv & 1;
    int l15 = ln & 15, l4 = ln >> 4;
    int m0 = blockIdx.y * BM, n0 = blockIdx.x * 128;

    f32x4 acc[MI][4];
#pragma unroll
    for (int i = 0; i < MI; ++i)
#pragma unroll
        for (int j = 0; j < 4; ++j) acc[i][j] = {0.f, 0.f, 0.f, 0.f};

    int aslot[MI], bslot[4];
#pragma unroll
    for (int i = 0; i < MI; ++i) {
        int m = wr * (BM / 2) + i * 16 + l15;
        aslot[i] = m * 4 + (l4 ^ ((m >> 1) & 3));
    }
#pragma unroll
    for (int j = 0; j < 4; ++j) {
        int n = wc * 64 + j * 16 + l15;
        bslot[j] = n * 4 + (l4 ^ ((n >> 1) & 3));
    }

    for (int k0 = 0; k0 < K; k0 += 32) {
#pragma unroll
        for (int r = 0; r < BM / 64; ++r) {
            int s = r * 256 + tid;
            int m = s >> 2, c = s & 3;
            int kb = c ^ ((m >> 1) & 3);
            int gm = m0 + m; if (gm > M - 1) gm = M - 1;   // clamp; results discarded at store
            g2lds16(A + (size_t)gm * K + k0 + kb * 8, &As[s * 8]);
        }
#pragma unroll
        for (int r = 0; r < 2; ++r) {
            int s = r * 256 + tid;
            int n = s >> 2, c = s & 3;
            int kb = c ^ ((n >> 1) & 3);
            g2lds16(Bt + (size_t)(n0 + n) * K + k0 + kb * 8, &Bs[s * 8]);
        }
        __syncthreads();
        bf16x8 af[MI], bfr[4];
#pragma unroll
        for (int i = 0; i < MI; ++i) af[i] = ld_frag(&As[aslot[i] * 8]);
#pragma unroll
        for (int j = 0; j < 4; ++j) bfr[j] = ld_frag(&Bs[bslot[j] * 8]);
#pragma unroll
        for (int i = 0; i < MI; ++i)
#pragma unroll
            for (int j = 0; j < 4; ++j)
                acc[i][j] = __builtin_amdgcn_mfma_f32_16x16x32_bf16(af[i], bfr[j], acc[i][j], 0, 0, 0);
        __syncthreads();
    }

#pragma unroll
    for (int i = 0; i < MI; ++i) {
#pragma unroll
        for (int j = 0; j < 4; ++j) {
            int gn = n0 + wc * 64 + j * 16 + l15;
            float bb = bias ? bias[gn] : 0.f;
#pragma unroll
            for (int r = 0; r < 4; ++r) {
                int gm = m0 + wr * (BM / 2) + i * 16 + l4 * 4 + r;
                if (gm >= M) continue;
                float v = acc[i][j][r] + bb;
                if (GELU_) v = 0.5f * v * (1.f + erff(v * 0.70710678118654752f));
                size_t orow = gm;
                if (REMAP) { int b_ = gm >> 11; orow = (size_t)b_ * SEQ1 + (gm & 2047) + 1; }
                size_t oi = orow * (size_t)N + gn;
                if (RESID) v += resid[oi];
                if (OBF) Ch[oi] = __float2bfloat16(v); else Cf[oi] = v;
            }
        }
    }
}

// ---------------- qkv GEMM with fused V-transpose output ----------------
// Per-batch m-grid: blockIdx.y = batch*33 + mb (BM=64, 33 blocks cover 2049 keys).
// n<1024 (Q,K) -> QKVout[b*SEQ1+key][n]; n>=1024 (V) -> VT[(b*8+h)*64+d][key] (packed 8B stores).
__global__ __launch_bounds__(256) void gemm_qkv(
    const bf16* __restrict__ A, const bf16* __restrict__ Bt,
    bf16* __restrict__ QKVout, bf16* __restrict__ VT, int K) {
    __shared__ __align__(16) bf16 As[64 * 32];
    __shared__ __align__(16) bf16 Bs[4096];
    int tid = threadIdx.x;
    int ln = tid & 63, wv = tid >> 6;
    int wr = wv >> 1, wc = wv & 1;
    int l15 = ln & 15, l4 = ln >> 4;
    int bb = blockIdx.y / 33;
    int m0 = (blockIdx.y % 33) * 64;          // local key base
    int n0 = blockIdx.x * 128;
    const bf16* Ab = A + (size_t)bb * SEQ1 * K;

    f32x4 acc[2][4];
#pragma unroll
    for (int i = 0; i < 2; ++i)
#pragma unroll
        for (int j = 0; j < 4; ++j) acc[i][j] = {0.f, 0.f, 0.f, 0.f};

    int aslot[2], bslot[4];
#pragma unroll
    for (int i = 0; i < 2; ++i) {
        int m = wr * 32 + i * 16 + l15;
        aslot[i] = m * 4 + (l4 ^ ((m >> 1) & 3));
    }
#pragma unroll
    for (int j = 0; j < 4; ++j) {
        int n = wc * 64 + j * 16 + l15;
        bslot[j] = n * 4 + (l4 ^ ((n >> 1) & 3));
    }

    for (int k0 = 0; k0 < K; k0 += 32) {
        {
            int s = tid;
            int m = s >> 2, c = s & 3;
            int kb = c ^ ((m >> 1) & 3);
            int gm = m0 + m; if (gm > SEQ1 - 1) gm = SEQ1 - 1;   // clamp within batch
            g2lds16(Ab + (size_t)gm * K + k0 + kb * 8, &As[s * 8]);
        }
#pragma unroll
        for (int r = 0; r < 2; ++r) {
            int s = r * 256 + tid;
            int n = s >> 2, c = s & 3;
            int kb = c ^ ((n >> 1) & 3);
            g2lds16(Bt + (size_t)(n0 + n) * K + k0 + kb * 8, &Bs[s * 8]);
        }
        __syncthreads();
        bf16x8 af[2], bfr[4];
#pragma unroll
        for (int i = 0; i < 2; ++i) af[i] = ld_frag(&As[aslot[i] * 8]);
#pragma unroll
        for (int j = 0; j < 4; ++j) bfr[j] = ld_frag(&Bs[bslot[j] * 8]);
#pragma unroll
        for (int i = 0; i < 2; ++i)
#pragma unroll
            for (int j = 0; j < 4; ++j)
                acc[i][j] = __builtin_amdgcn_mfma_f32_16x16x32_bf16(af[i], bfr[j], acc[i][j], 0, 0, 0);
        __syncthreads();
    }

#pragma unroll
    for (int i = 0; i < 2; ++i) {
#pragma unroll
        for (int j = 0; j < 4; ++j) {
            int gn = n0 + wc * 64 + j * 16 + l15;
            int keyb = m0 + wr * 32 + i * 16 + l4 * 4;       // multiple of 4
            if (gn < 1024) {
#pragma unroll
                for (int r = 0; r < 4; ++r) {
                    int key = keyb + r;
                    if (key < SEQ1)
                        QKVout[((size_t)bb * SEQ1 + key) * 1536 + gn] =
                            __float2bfloat16(acc[i][j][r]);
                }
            } else {
                int hh = (gn - 1024) >> 6, dd = (gn - 1024) & 63;
                bf16* vrow = VT + ((size_t)(bb * 8 + hh) * 64 + dd) * VKP;
                if (keyb + 3 < SEQ1) {
                    union { unsigned short u[4]; uint2 v; } ou;
#pragma unroll
                    for (int r = 0; r < 4; ++r)
                        ou.u[r] = __builtin_bit_cast(unsigned short, __float2bfloat16(acc[i][j][r]));
                    *(uint2*)&vrow[keyb] = ou.v;             // 8B-aligned: keyb % 4 == 0
                } else {
#pragma unroll
                    for (int r = 0; r < 4; ++r) {
                        int key = keyb + r;
                        if (key < SEQ1) vrow[key] = __float2bfloat16(acc[i][j][r]);
                    }
                }
            }
        }
    }
}

// ---------------- LayerNorm: one wave per row, no LDS, no barriers ----------------
__global__ __launch_bounds__(256) void ln_kernel(const float* __restrict__ Xin, bf16* __restrict__ Xout,
                          const float* __restrict__ g, const float* __restrict__ bb) {
    int wv = threadIdx.x >> 6, ln = threadIdx.x & 63;
    int row = blockIdx.x * 4 + wv;
    if (row >= ROWS) return;
    const float* xr = Xin + (size_t)row * DIMC + ln * 8;
    float4 a = *(const float4*)xr;
    float4 c = *(const float4*)(xr + 4);
    float s = a.x + a.y + a.z + a.w + c.x + c.y + c.z + c.w;
#pragma unroll
    for (int off = 1; off < 64; off <<= 1) s += __shfl_xor(s, off, 64);
    float mean = s * (1.f / 512.f);
    float d[8] = {a.x - mean, a.y - mean, a.z - mean, a.w - mean,
                  c.x - mean, c.y - mean, c.z - mean, c.w - mean};
    float var = 0.f;
#pragma unroll
    for (int e = 0; e < 8; ++e) var += d[e] * d[e];
#pragma unroll
    for (int off = 1; off < 64; off <<= 1) var += __shfl_xor(var, off, 64);
    float rinv = rsqrtf(var * (1.f / 512.f) + 1e-5f);
    const float* gp = g + ln * 8;
    const float* bp = bb + ln * 8;
    float4 g0 = *(const float4*)gp, g1 = *(const float4*)(gp + 4);
    float4 b0 = *(const float4*)bp, b1 = *(const float4*)(bp + 4);
    float gg[8] = {g0.x, g0.y, g0.z, g0.w, g1.x, g1.y, g1.z, g1.w};
    float bbv[8] = {b0.x, b0.y, b0.z, b0.w, b1.x, b1.y, b1.z, b1.w};
    union { unsigned short u[8]; uint4 v; } ou;
#pragma unroll
    for (int e = 0; e < 8; ++e)
        ou.u[e] = __builtin_bit_cast(unsigned short, __float2bfloat16(d[e] * rinv * gg[e] + bbv[e]));
    *(uint4*)(Xout + (size_t)row * DIMC + ln * 8) = ou.v;
}

// ---------------- MFMA flash attention v4 (R11-proven, verbatim): XOR-swizzled LDS, mask fast path ----------------
__global__ __launch_bounds__(256, 5) void attn_kernel(
    const bf16* __restrict__ QKV, const bf16* __restrict__ VT,
    const int* __restrict__ lens, bf16* __restrict__ O) {
    __shared__ __align__(16) bf16 Ks[2][4096];
    __shared__ __align__(16) bf16 Vs[2][4096];   // V^T tile: [dim][key]
    int tid = threadIdx.x, ln = tid & 63, wv = tid >> 6;
    int l15 = ln & 15, l4 = ln >> 4;
    int q0 = blockIdx.x * 64, h = blockIdx.y, b = blockIdx.z;
    int len1 = lens[b] + 1;
    const bf16* qkv_b = QKV + (size_t)b * SEQ1 * 1536;
    const bf16* vt_b  = VT + (size_t)(b * 8 + h) * 64 * VKP;

    uint4 z4 = make_uint4(0u, 0u, 0u, 0u);
    uint4 q0v = z4, q1v = z4;
    int qrow = q0 + wv * 16 + l15;
    if (qrow < SEQ1) {
        const bf16* qp = qkv_b + (size_t)qrow * 1536 + h * 64 + l4 * 8;
        q0v = *(const uint4*)qp;
        q1v = *(const uint4*)(qp + 32);
    }
    bf16x8 bq0 = __builtin_bit_cast(bf16x8, q0v);
    bf16x8 bq1 = __builtin_bit_cast(bf16x8, q1v);
    bool qpad = (qrow >= len1);

    float mrun = NEGBIG, lrun = 0.f;
    f32x4 oaccT[4];
#pragma unroll
    for (int t = 0; t < 4; ++t) oaccT[t] = {0.f, 0.f, 0.f, 0.f};

    uint4 kr[2], vr[2];
    int srow[2], sseg[2];
    int kslot[2], vslot[2];
#pragma unroll
    for (int rr = 0; rr < 2; ++rr) {
        int idx = rr * 256 + tid;
        int row = idx >> 3, seg = idx & 7;
        srow[rr] = row; sseg[rr] = seg;
        int pb = row >> 5, w = row & 31;
        int krow = pb * 32 + ((w >> 2) & 1) * 16 + (w >> 3) * 4 + (w & 3);  // permuted K row
        kslot[rr] = krow * 8 + (seg ^ (krow & 7));
        vslot[rr] = row * 8 + (seg ^ (row & 7));
    }

#pragma unroll
    for (int rr = 0; rr < 2; ++rr) {
        kr[rr] = (srow[rr] < SEQ1)
            ? *(const uint4*)(qkv_b + (size_t)srow[rr] * 1536 + 512 + h * 64 + sseg[rr] * 8) : z4;
        vr[rr] = *(const uint4*)(vt_b + (size_t)srow[rr] * VKP + sseg[rr] * 8);
    }
#pragma unroll
    for (int rr = 0; rr < 2; ++rr) {
        *(uint4*)&Ks[0][kslot[rr] * 8] = kr[rr];
        *(uint4*)&Vs[0][vslot[rr] * 8] = vr[rr];
    }
    __syncthreads();

    for (int kt = 0; kt < 33; ++kt) {
        int k0 = kt * 64;
        int buf = kt & 1;
        if (kt < 32) {
            int kn = k0 + 64;
#pragma unroll
            for (int rr = 0; rr < 2; ++rr) {
                kr[rr] = (kn + srow[rr] < SEQ1)
                    ? *(const uint4*)(qkv_b + (size_t)(kn + srow[rr]) * 1536 + 512 + h * 64 + sseg[rr] * 8) : z4;
                vr[rr] = *(const uint4*)(vt_b + (size_t)srow[rr] * VKP + kn + sseg[rr] * 8);
            }
        }

        // S^T = K Q^T : subtile (pb,s) holds keys k0 + pb*32 + l4*8 + s*4 + r at col q=l15
        f32x4 sacc[2][2];
#pragma unroll
        for (int pb = 0; pb < 2; ++pb)
#pragma unroll
            for (int s = 0; s < 2; ++s) {
                int R = pb * 32 + s * 16 + l15;
                f32x4 a = {0.f, 0.f, 0.f, 0.f};
                bf16x8 kf0 = ld_frag(&Ks[buf][(R * 8 + (l4 ^ (R & 7))) * 8]);
                bf16x8 kf1 = ld_frag(&Ks[buf][(R * 8 + ((l4 + 4) ^ (R & 7))) * 8]);
                a = __builtin_amdgcn_mfma_f32_16x16x32_bf16(kf0, bq0, a, 0, 0, 0);
                a = __builtin_amdgcn_mfma_f32_16x16x32_bf16(kf1, bq1, a, 0, 0, 0);
                sacc[pb][s] = a;
            }

        // online softmax; mask only when tile can contain masked columns (wave-uniform)
        bool needmask = (k0 + 64 > len1) || (kt == 32);
        float sv[2][2][4];
        float mx = NEGBIG;
#pragma unroll
        for (int pb = 0; pb < 2; ++pb)
#pragma unroll
            for (int s = 0; s < 2; ++s)
#pragma unroll
                for (int r = 0; r < 4; ++r) {
                    float v = sacc[pb][s][r] * ATT_SCALE;
                    if (needmask) {
                        int j = k0 + pb * 32 + l4 * 8 + s * 4 + r;
                        if (j >= SEQ1 || (qpad && j >= len1)) v = NEGBIG;
                    }
                    sv[pb][s][r] = v;
                    mx = fmaxf(mx, v);
                }
        mx = fmaxf(mx, __shfl_xor(mx, 16, 64));
        mx = fmaxf(mx, __shfl_xor(mx, 32, 64));
        float mnew = fmaxf(mrun, mx);
        float alpha = __expf(mrun - mnew);
        float rs = 0.f;
        unsigned short pk[2][8];
#pragma unroll
        for (int pb = 0; pb < 2; ++pb)
#pragma unroll
            for (int s = 0; s < 2; ++s)
#pragma unroll
                for (int r = 0; r < 4; ++r) {
                    float ex = sv[pb][s][r] - mnew;
                    float p = (ex < -80.f) ? 0.f : __expf(ex);
                    rs += p;
                    pk[pb][s * 4 + r] = __builtin_bit_cast(unsigned short, __float2bfloat16(p));
                }
        rs += __shfl_xor(rs, 16, 64);
        rs += __shfl_xor(rs, 32, 64);
        lrun = lrun * alpha + rs;
        mrun = mnew;
#pragma unroll
        for (int t = 0; t < 4; ++t) {
            oaccT[t][0] *= alpha; oaccT[t][1] *= alpha;
            oaccT[t][2] *= alpha; oaccT[t][3] *= alpha;
        }

        // O^T += V^T P^T : A = V^T frag from LDS, B = P^T from registers
#pragma unroll
        for (int pb = 0; pb < 2; ++pb) {
            union { unsigned short u[8]; bf16x8 v; } pu;
#pragma unroll
            for (int e = 0; e < 8; ++e) pu.u[e] = pk[pb][e];
            bf16x8 pf = pu.v;
#pragma unroll
            for (int t = 0; t < 4; ++t) {
                int VR = t * 16 + l15;
                bf16x8 vf = ld_frag(&Vs[buf][(VR * 8 + ((pb * 4 + l4) ^ (VR & 7))) * 8]);
                oaccT[t] = __builtin_amdgcn_mfma_f32_16x16x32_bf16(vf, pf, oaccT[t], 0, 0, 0);
            }
        }

        if (kt < 32) {
            int ob = buf ^ 1;
#pragma unroll
            for (int rr = 0; rr < 2; ++rr) {
                *(uint4*)&Ks[ob][kslot[rr] * 8] = kr[rr];
                *(uint4*)&Vs[ob][vslot[rr] * 8] = vr[rr];
            }
        }
        __syncthreads();
    }

    if (qrow < SEQ1) {
        float rl = (lrun > 0.f) ? 1.f / lrun : 0.f;
        bf16* orow = O + ((size_t)b * SEQ1 + qrow) * DIMC + h * 64;
#pragma unroll
        for (int t = 0; t < 4; ++t) {
            union { unsigned short u[4]; uint2 v; } ou;
#pragma unroll
            for (int r = 0; r < 4; ++r)
                ou.u[r] = __builtin_bit_cast(unsigned short, __float2bfloat16(oaccT[t][r] * rl));
            *(uint2*)&orow[t * 16 + l4 * 4] = ou.v;
        }
    }
}

// ---------------- fused final LN + head (cls row only), fp32 ----------------
__global__ __launch_bounds__(256) void head_kernel(const float* __restrict__ X,
                            const float* __restrict__ g, const float* __restrict__ bb,
                            const float* __restrict__ hw, const float* __restrict__ hb,
                            float* __restrict__ out) {
    int b = blockIdx.x, t = threadIdx.x;
    const float* xr = X + (size_t)b * SEQ1 * DIMC;
    float v0 = xr[t], v1 = xr[t + 256];
    __shared__ float red[256];
    red[t] = v0 + v1;
    __syncthreads();
    for (int w = 128; w > 0; w >>= 1) { if (t < w) red[t] += red[t + w]; __syncthreads(); }
    float mean = red[0] * (1.f / 512.f);
    __syncthreads();
    float d0 = v0 - mean, d1 = v1 - mean;
    red[t] = d0 * d0 + d1 * d1;
    __syncthreads();
    for (int w = 128; w > 0; w >>= 1) { if (t < w) red[t] += red[t + w]; __syncthreads(); }
    float rinv = rsqrtf(red[0] * (1.f / 512.f) + 1e-5f);
    __syncthreads();
    float xn0 = d0 * rinv * g[t] + bb[t];
    float xn1 = d1 * rinv * g[t + 256] + bb[t + 256];
    float p0 = xn0 * hw[t * 2]     + xn1 * hw[(t + 256) * 2];
    float p1 = xn0 * hw[t * 2 + 1] + xn1 * hw[(t + 256) * 2 + 1];
    __shared__ float r0[256], r1[256];
    r0[t] = p0; r1[t] = p1;
    __syncthreads();
    for (int w = 128; w > 0; w >>= 1) { if (t < w) { r0[t] += r0[t + w]; r1[t] += r1[t + w]; } __syncthreads(); }
    if (t == 0) {
        out[b * 2 + 0] = r0[0] + hb[0];
        out[b * 2 + 1] = r1[0] + hb[1];
    }
}

extern "C" void kernel_launch(void* const* d_in, const int* in_sizes, int n_in,
                              void* d_out, int out_size, void* d_ws, size_t ws_size,
                              hipStream_t stream) {
    const float* x      = (const float*)d_in[0];
    const int*   lens   = (const int*)d_in[1];
    const float* cls    = (const float*)d_in[2];
    const float* fc_w   = (const float*)d_in[3];
    const float* fc_b   = (const float*)d_in[4];
    const float* ln1_g  = (const float*)d_in[5];
    const float* ln1_b  = (const float*)d_in[6];
    const float* qkv_w  = (const float*)d_in[7];
    const float* out_w  = (const float*)d_in[8];
    const float* out_b  = (const float*)d_in[9];
    const float* ln2_g  = (const float*)d_in[10];
    const float* ln2_b  = (const float*)d_in[11];
    const float* ff1_w  = (const float*)d_in[12];
    const float* ff1_b  = (const float*)d_in[13];
    const float* ff2_w  = (const float*)d_in[14];
    const float* ff2_b  = (const float*)d_in[15];
    const float* lnf_g  = (const float*)d_in[16];
    const float* lnf_b  = (const float*)d_in[17];
    const float* head_w = (const float*)d_in[18];
    const float* head_b = (const float*)d_in[19];
    float* out = (float*)d_out;

    char* w = (char*)d_ws;
    float* X    = (float*)w;  w += (size_t)ROWS * DIMC * 4;
    bf16*  XNh  = (bf16*)w;   w += (size_t)ROWS * DIMC * 2;
    bf16*  QKVh = (bf16*)w;   w += (size_t)ROWS * 1536 * 2;
    bf16*  Obh  = (bf16*)w;   w += (size_t)ROWS * DIMC * 2;
    bf16*  xbf  = (bf16*)w;   w += (size_t)BATCH * SEQ * DIN * 2;
    bf16*  VT   = xbf;        // alias: xbf dead after stem gemm
    bf16*  fc_wt  = (bf16*)w;
    bf16*  qkv_wt = fc_wt  + (size_t)DIN * DIMC;
    bf16*  out_wt = qkv_wt + (size_t)2 * DIMC * 1536;
    bf16*  ff1_wt = out_wt + (size_t)2 * DIMC * DIMC;
    bf16*  ff2_wt = ff1_wt + (size_t)2 * DIMC * DIMC;
    bf16*  Hbh  = Obh;

    dim3 blk(256);
    dim3 tb(32, 8);

    cast_kernel<<<dim3((BATCH * SEQ * DIN / 4 + 255) / 256), blk, 0, stream>>>(
        x, xbf, BATCH * SEQ * DIN / 4);

    wt_transpose_kernel<<<dim3(16, 24, 1), tb, 0, stream>>>(fc_w,  fc_wt,  DIN,  DIMC, (long)DIN * DIMC);
    wt_transpose_kernel<<<dim3(48, 16, 2), tb, 0, stream>>>(qkv_w, qkv_wt, DIMC, 1536, (long)DIMC * 1536);
    wt3_transpose_kernel<<<dim3(16, 16, 6), tb, 0, stream>>>(out_w, ff1_w, ff2_w, out_wt);

    // stem: fc + gelu -> X fp32 (remapped rows), BM=64 -> 512 blocks
    gemm_bt<64, true, false, true, false><<<dim3(4, 128), blk, 0, stream>>>(
        xbf, fc_wt, fc_b, nullptr, X, nullptr, BATCH * SEQ, DIMC, DIN);
    cls_fill_kernel<<<dim3(BATCH), blk, 0, stream>>>(cls, X);

    for (int l = 0; l < DEPTH; ++l) {
        ln_kernel<<<dim3((ROWS + 3) / 4), blk, 0, stream>>>(X, XNh, ln1_g + l * DIMC, ln1_b + l * DIMC);
        // qkv with fused V-transpose: grid (12, 4*33)
        gemm_qkv<<<dim3(12, 132), blk, 0, stream>>>(
            XNh, qkv_wt + (size_t)l * DIMC * 1536, QKVh, VT, DIMC);
        attn_kernel<<<dim3(33, NHEAD, BATCH), blk, 0, stream>>>(QKVh, VT, lens, Obh);
        gemm_bt<64, false, true, false, false><<<dim3(4, 129), blk, 0, stream>>>(
            Obh, out_wt + (size_t)l * DIMC * DIMC, out_b + l * DIMC, X, X, nullptr, ROWS, DIMC, DIMC);
        ln_kernel<<<dim3((ROWS + 3) / 4), blk, 0, stream>>>(X, XNh, ln2_g + l * DIMC, ln2_b + l * DIMC);
        gemm_bt<64, true, false, false, true><<<dim3(4, 129), blk, 0, stream>>>(
            XNh, ff1_wt + (size_t)l * DIMC * DIMC, ff1_b + l * DIMC, nullptr, nullptr, Hbh, ROWS, DIMC, DIMC);
        gemm_bt<64, false, true, false, false><<<dim3(4, 129), blk, 0, stream>>>(
            Hbh, ff2_wt + (size_t)l * DIMC * DIMC, ff2_b + l * DIMC, X, X, nullptr, ROWS, DIMC, DIMC);
    }
    head_kernel<<<dim3(BATCH), blk, 0, stream>>>(X, lnf_g, lnf_b, head_w, head_b, out);
}